// Round 1
// baseline (1006.435 us; speedup 1.0000x reference)
//
#include <hip/hip_runtime.h>
#include <hip/hip_bf16.h>

// LiteMLA: B=8, C=256, H=W=64, N=HW=4096, td=256, d=8, heads=64
// qkv: (8,768,4096)  dw/agg: (8,768,4096)  kv: (8,64,8,9)

#define HW 4096
#define ATT_EPS 1e-15f
#define BN_EPS 1e-6f

// ---------------- K1: qkv = w_qkv(768x256) @ x(b,256,4096) ----------------
// block 256 thr; each thread: 16 o x 4 n (float4). grid (4 ntiles, 48 otiles, 8 b)
__global__ __launch_bounds__(256) void qkv_gemm(const float* __restrict__ x,
                                                const float* __restrict__ w,
                                                float* __restrict__ qkv) {
    const int b  = blockIdx.z;
    const int o0 = blockIdx.y * 16;
    const int nb = blockIdx.x * 1024;           // floats
    const int t  = threadIdx.x;

    const float4* xp = (const float4*)(x + ((size_t)b * 256) * HW + nb) + t;
    const float*  wp = w + o0 * 256;            // wave-uniform -> scalar loads

    float4 acc[16];
#pragma unroll
    for (int i = 0; i < 16; i++) acc[i] = make_float4(0.f, 0.f, 0.f, 0.f);

#pragma unroll 2
    for (int c = 0; c < 256; c++) {
        float4 xv = xp[c * 1024];
#pragma unroll
        for (int oo = 0; oo < 16; oo++) {
            float wv = wp[oo * 256 + c];
            acc[oo].x += wv * xv.x;
            acc[oo].y += wv * xv.y;
            acc[oo].z += wv * xv.z;
            acc[oo].w += wv * xv.w;
        }
    }
    float4* po = (float4*)(qkv + ((size_t)b * 768 + o0) * HW + nb) + t;
#pragma unroll
    for (int oo = 0; oo < 16; oo++) po[oo * 1024] = acc[oo];
}

// ---------------- K2: depthwise 5x5, pad 2 ----------------
// block 256 = 64x * 4y; grid (16 ytiles, 768 ch, 8 b)
__global__ __launch_bounds__(256) void dw_conv(const float* __restrict__ qkv,
                                               const float* __restrict__ wdw,
                                               float* __restrict__ dst) {
    __shared__ float tile[8][64];   // rows y0-2 .. y0+5
    __shared__ float wk[25];
    const int b  = blockIdx.z;
    const int ch = blockIdx.y;
    const int y0 = blockIdx.x * 4;
    const int tx = threadIdx.x & 63;
    const int ty = threadIdx.x >> 6;

    const float* src = qkv + ((size_t)b * 768 + ch) * HW;
    for (int i = threadIdx.x; i < 512; i += 256) {
        int r = i >> 6, xx = i & 63;
        int y = y0 - 2 + r;
        tile[r][xx] = (y >= 0 && y < 64) ? src[y * 64 + xx] : 0.f;
    }
    if (threadIdx.x < 25) wk[threadIdx.x] = wdw[ch * 25 + threadIdx.x];
    __syncthreads();

    float acc = 0.f;
#pragma unroll
    for (int dy = 0; dy < 5; dy++) {
#pragma unroll
        for (int dx = 0; dx < 5; dx++) {
            int xx = tx + dx - 2;
            float v = (xx >= 0 && xx < 64) ? tile[ty + dy][xx] : 0.f;
            acc += wk[dy * 5 + dx] * v;
        }
    }
    dst[((size_t)b * 768 + ch) * HW + (y0 + ty) * 64 + tx] = acc;
}

// ---------------- K3: grouped pointwise 8x8, in place ----------------
// grid (16 ntiles, 96 g, 8 b), block 256
__global__ __launch_bounds__(256) void agg_pw(float* __restrict__ buf,
                                              const float* __restrict__ wpw) {
    __shared__ float wl[64];
    const int b = blockIdx.z, g = blockIdx.y;
    const int n = blockIdx.x * 256 + threadIdx.x;
    if (threadIdx.x < 64) wl[threadIdx.x] = wpw[g * 64 + threadIdx.x];
    __syncthreads();

    float* base = buf + ((size_t)b * 768 + g * 8) * HW + n;
    float d[8];
#pragma unroll
    for (int i = 0; i < 8; i++) d[i] = base[(size_t)i * HW];
#pragma unroll
    for (int o = 0; o < 8; o++) {
        float acc = 0.f;
#pragma unroll
        for (int i = 0; i < 8; i++) acc += wl[o * 8 + i] * d[i];
        base[(size_t)o * HW] = acc;
    }
}

// ---------------- K4: kv[d][e] = sum_n relu(k[n,d]) * vpad[n,e] ----------------
// grid (64 h, 8 b), block 256. kv out: (b*64+h)*72 + d*9+e
__global__ __launch_bounds__(256) void kv_pass(const float* __restrict__ qkv,
                                               const float* __restrict__ agg,
                                               float* __restrict__ kvout) {
    const int h = blockIdx.x, b = blockIdx.y;
    const float* buf = (h < 32) ? qkv : agg;
    const int cbase  = (h < 32) ? h * 24 : h * 24 - 768;
    const float* kp = buf + ((size_t)b * 768 + cbase + 8) * HW;
    const float* vp = buf + ((size_t)b * 768 + cbase + 16) * HW;

    float acc[8][9];
#pragma unroll
    for (int d = 0; d < 8; d++)
#pragma unroll
        for (int e = 0; e < 9; e++) acc[d][e] = 0.f;

    for (int n = threadIdx.x; n < HW; n += 256) {
        float kk[8], vv[8];
#pragma unroll
        for (int d = 0; d < 8; d++) kk[d] = fmaxf(kp[(size_t)d * HW + n], 0.f);
#pragma unroll
        for (int e = 0; e < 8; e++) vv[e] = vp[(size_t)e * HW + n];
#pragma unroll
        for (int d = 0; d < 8; d++) {
#pragma unroll
            for (int e = 0; e < 8; e++) acc[d][e] += kk[d] * vv[e];
            acc[d][8] += kk[d];
        }
    }

    __shared__ float red[4][72];
    const int lane = threadIdx.x & 63, wv = threadIdx.x >> 6;
#pragma unroll
    for (int d = 0; d < 8; d++) {
#pragma unroll
        for (int e = 0; e < 9; e++) {
            float v = acc[d][e];
            v += __shfl_xor(v, 1);
            v += __shfl_xor(v, 2);
            v += __shfl_xor(v, 4);
            v += __shfl_xor(v, 8);
            v += __shfl_xor(v, 16);
            v += __shfl_xor(v, 32);
            if (lane == 0) red[wv][d * 9 + e] = v;
        }
    }
    __syncthreads();
    if (threadIdx.x < 72) {
        float s = red[0][threadIdx.x] + red[1][threadIdx.x] +
                  red[2][threadIdx.x] + red[3][threadIdx.x];
        kvout[((size_t)(b * 64 + h)) * 72 + threadIdx.x] = s;
    }
}

// ---------------- K5: att = (relu(q)@kv)/den, p = w_proj@att, BN, +x ----------------
// grid (64 ntiles of 64 px, 8 b), block 256: px = tid&63, og = tid>>6 (64 o each)
__global__ __launch_bounds__(256) void att_proj(const float* __restrict__ qkv,
                                                const float* __restrict__ agg,
                                                const float* __restrict__ kvbuf,
                                                const float* __restrict__ wproj,
                                                const float* __restrict__ gamma,
                                                const float* __restrict__ beta,
                                                const float* __restrict__ mean,
                                                const float* __restrict__ var,
                                                const float* __restrict__ x,
                                                float* __restrict__ out) {
    __shared__ float kv_l[64 * 72];       // 18 KB
    __shared__ float att_l[4][8][64];     // 8 KB: [hh][e][px]
    const int b  = blockIdx.y;
    const int n0 = blockIdx.x * 64;
    const int t  = threadIdx.x;
    const int px = t & 63, og = t >> 6;   // og is wave-uniform

    for (int i = t; i < 64 * 72; i += 256) kv_l[i] = kvbuf[(size_t)b * 64 * 72 + i];
    __syncthreads();

    float p[64];
#pragma unroll
    for (int i = 0; i < 64; i++) p[i] = 0.f;

    for (int hc = 0; hc < 16; hc++) {
        const int h = hc * 4 + og;
        const float* buf = (h < 32) ? qkv : agg;
        const int cbase  = (h < 32) ? h * 24 : h * 24 - 768;
        const float* qp = buf + ((size_t)b * 768 + cbase) * HW + n0 + px;

        float num[9];
#pragma unroll
        for (int e = 0; e < 9; e++) num[e] = 0.f;
#pragma unroll
        for (int d = 0; d < 8; d++) {
            float qv = fmaxf(qp[(size_t)d * HW], 0.f);
            const float* kvh = &kv_l[h * 72 + d * 9];
#pragma unroll
            for (int e = 0; e < 9; e++) num[e] += qv * kvh[e];
        }
        float rden = 1.f / (num[8] + ATT_EPS);

        __syncthreads();   // protect previous chunk's att_l reads
#pragma unroll
        for (int e = 0; e < 8; e++) att_l[og][e][px] = num[e] * rden;
        __syncthreads();

        float av[32];
#pragma unroll
        for (int cc = 0; cc < 32; cc++) av[cc] = att_l[cc >> 3][cc & 7][px];
#pragma unroll
        for (int oo = 0; oo < 64; oo++) {
            const float* wr = wproj + (og * 64 + oo) * 512 + hc * 32; // wave-uniform
            float s = p[oo];
#pragma unroll
            for (int cc = 0; cc < 32; cc++) s += wr[cc] * av[cc];
            p[oo] = s;
        }
    }

    const size_t obase = ((size_t)b * 256 + og * 64) * HW + n0 + px;
#pragma unroll
    for (int oo = 0; oo < 64; oo++) {
        int o = og * 64 + oo;
        float inv = gamma[o] * rsqrtf(var[o] + BN_EPS);
        float sh  = beta[o] - mean[o] * inv;
        out[obase + (size_t)oo * HW] = x[obase + (size_t)oo * HW] + p[oo] * inv + sh;
    }
}

extern "C" void kernel_launch(void* const* d_in, const int* in_sizes, int n_in,
                              void* d_out, int out_size, void* d_ws, size_t ws_size,
                              hipStream_t stream) {
    const float* x      = (const float*)d_in[0];
    const float* w_qkv  = (const float*)d_in[1];
    const float* w_dw   = (const float*)d_in[2];
    const float* w_pw   = (const float*)d_in[3];
    const float* w_proj = (const float*)d_in[4];
    const float* gamma  = (const float*)d_in[5];
    const float* beta   = (const float*)d_in[6];
    const float* mean   = (const float*)d_in[7];
    const float* var    = (const float*)d_in[8];
    float* out = (float*)d_out;

    float* qkv = (float*)d_ws;                 // 8*768*4096 = 25165824 floats
    float* dwb = qkv + (size_t)25165824;       // depthwise out, then agg in-place
    float* kvb = dwb + (size_t)25165824;       // 8*64*72 floats

    qkv_gemm<<<dim3(4, 48, 8),   256, 0, stream>>>(x, w_qkv, qkv);
    dw_conv <<<dim3(16, 768, 8), 256, 0, stream>>>(qkv, w_dw, dwb);
    agg_pw  <<<dim3(16, 96, 8),  256, 0, stream>>>(dwb, w_pw);
    kv_pass <<<dim3(64, 8),      256, 0, stream>>>(qkv, dwb, kvb);
    att_proj<<<dim3(64, 8),      256, 0, stream>>>(qkv, dwb, kvb, w_proj,
                                                   gamma, beta, mean, var, x, out);
}